// Round 6
// baseline (2533.679 us; speedup 1.0000x reference)
//
#include <hip/hip_runtime.h>

// GRU encoder-decoder, MFMA split-precision, AGPR-resident weights (r6).
// B=8192, H=64, 512 enc + 180 dec steps. 256 blocks x 256 threads (4 waves),
// 32 batches/block, ONE wave per SIMD (~300 regs: ILP replaces TLP).
// r5 evidence: "+v" pins forced the 36 weight frags (144 regs) into the
// 128-reg arch-VGPR region -> allocator bounced them through AGPRs with
// v_accvgpr copies every step (VALUBusy 69%, dur unchanged). Fix: pin wB
// with "+a" so MFMA reads B-operands directly from AGPRs (ISA: A/B can be
// AGPR), and drop to 1 wave/SIMD with 2x batches/wave so the full set
// (144 AGPR + ~130 VGPR) fits the 512-reg single-wave budget with zero
// spill. 2 row-blocks give 6-8 independent MFMA chains (latency cover);
// h1-old fragments prefetched before the mid-barrier.
// Ownership (per 16-batch row-block) identical to r4/r5: wave w owns
// N-tiles {w,4+w,8+w}; lane (rg,jc) gates (batch rb*16+4rg+i, j=16w+jc)
// lane-locally; bf16 hi/lo A-frags in LDS, XOR-swizzle b^rg (0 conflicts).

typedef __attribute__((ext_vector_type(8))) short bf16x8;
typedef __attribute__((ext_vector_type(4))) float f32x4;

struct Params {
  const float *x;
  const float *wih0e, *bih0e, *bhh0e, *bih1e, *bhh1e;
  const float *wih0d, *bih0d, *bhh0d, *bih1d, *bhh1d;
  const float *outW, *outb;
  const unsigned short *wt;   // [6][12 nt][2 kf][2 sp][64 lane][8 e] bf16 frags
  float *out;
};

__device__ __forceinline__ float sgm(float v) { return 1.f / (1.f + __expf(-v)); }
__device__ __forceinline__ float th(float v)  { float e = __expf(2.f * v); return 1.f - 2.f / (e + 1.f); }

// fp32 -> bf16 round-to-nearest-even (bit trick)
__device__ __forceinline__ unsigned short rbf(float v) {
  unsigned int u = __float_as_uint(v);
  return (unsigned short)((u + 0x7fffu + ((u >> 16) & 1u)) >> 16);
}
__device__ __forceinline__ float ubf(unsigned short h) {
  return __uint_as_float((unsigned int)h << 16);
}

__device__ __forceinline__ f32x4 mfma16(bf16x8 a, bf16x8 b, f32x4 c) {
  return __builtin_amdgcn_mfma_f32_16x16x32_bf16(a, b, c, 0, 0, 0);
}

// Preprocess the six 192x64 fp32 matrices into B-fragment bf16 hi/lo planes.
// B[k][n] = W[n][k]; frag (nt,kf,sp): lane l elem e holds
// B[k = kf*32 + (l>>4)*8 + e][n = nt*16 + (l&15)].
// Flat: dst[m][ ((nt*2+kf)*2+sp)*512 + l*8 + e ]   (validated r3-r5)
__global__ void prep_w(const float* s0, const float* s1, const float* s2,
                       const float* s3, const float* s4, const float* s5,
                       unsigned short* dst) {
  const float* srcs[6] = {s0, s1, s2, s3, s4, s5};
  const float* s = srcs[blockIdx.x];
  unsigned short* o = dst + blockIdx.x * 24576;
  for (int i = threadIdx.x; i < 24576; i += blockDim.x) {
    int e  = i & 7;
    int l  = (i >> 3) & 63;
    int sp = (i >> 9) & 1;
    int kf = (i >> 10) & 1;
    int nt = i >> 11;
    int n = nt * 16 + (l & 15);
    int k = kf * 32 + (l >> 4) * 8 + e;
    float v = s[n * 64 + k];
    unsigned short hi = rbf(v);
    unsigned short val = hi;
    if (sp) val = rbf(v - ubf(hi));
    o[i] = val;
  }
}

// A-frag LDS layout per (parity, row-block), 2048 ushorts = 4KB:
//   idx(kf,sp,rg,bslot,e) = (kf*2+sp)*512 + rg*128 + bslot*8 + e
//   value = h_split[sp][b16 = bslot ^ rg][k = kf*32 + rg*8 + e]
// Read (lane l): rg=l>>4, bslot=(l&15)^rg -> b128, quarter-wave linear.
// Write (j-owner): kf=j>>5, rg=(j>>3)&3, e=j&7, bslot=b16^rg -> <=2-way.
// Flat buffers: aH[parity*4096 + rb*2048 + idx].

__global__ __launch_bounds__(256) void gru_main(Params p) {
  __shared__ unsigned short aH0[2 * 4096];
  __shared__ unsigned short aH1[2 * 4096];
  __shared__ float pw[4][32];

  const int tid = threadIdx.x;
  const int l   = tid & 63;
  const int w   = tid >> 6;        // wave 0..3
  const int jc  = l & 15;
  const int rg  = l >> 4;
  const int j   = w * 16 + jc;     // this lane's hidden/gate index
  const int b0  = blockIdx.x * 32;

  const int kfj = j >> 5, rgj = (j >> 3) & 3, ej = j & 7;
  const int wbase = kfj * 1024 + rgj * 128 + ej;   // +bslot*8; +512 for lo
  const int rdb = rg * 128 + ((jc ^ rg) << 3);

  for (int i = tid; i < 8192; i += 256) { aH0[i] = 0; aH1[i] = 0; }
  float h0own[2][4], h1own[2][4];
#pragma unroll
  for (int rb = 0; rb < 2; ++rb)
#pragma unroll
    for (int i = 0; i < 4; ++i) { h0own[rb][i] = 0.f; h1own[rb][i] = 0.f; }

  bf16x8 wB[3][3][2][2];   // [matrix][gate g][kf][split] - AGPR-resident

  for (int ph = 0; ph < 2; ++ph) {
    // ---- load this phase's weight fragments; tile for gate g is g*4+w ----
#pragma unroll
    for (int m = 0; m < 3; ++m)
#pragma unroll
      for (int g = 0; g < 3; ++g)
#pragma unroll
        for (int kf = 0; kf < 2; ++kf)
#pragma unroll
          for (int sp = 0; sp < 2; ++sp) {
            int nt = g * 4 + w;
            wB[m][g][kf][sp] = *(const bf16x8*)(p.wt +
                (((((ph * 3 + m) * 12 + nt) * 2 + kf) * 2 + sp) << 9) + l * 8);
          }
    // ---- per-lane constants for row j ----
    float bi0[3], bh0[3], bi1[3], bh1[3], wxa[3], wxb[3];
#pragma unroll
    for (int g = 0; g < 3; ++g) {
      int r = g * 64 + j;
      if (ph == 0) {
        bi0[g] = p.bih0e[r]; bh0[g] = p.bhh0e[r];
        bi1[g] = p.bih1e[r]; bh1[g] = p.bhh1e[r];
        wxa[g] = p.wih0e[2 * r]; wxb[g] = p.wih0e[2 * r + 1];
      } else {
        bi0[g] = p.bih0d[r]; bh0[g] = p.bhh0d[r];
        bi1[g] = p.bih1d[r]; bh1[g] = p.bhh1d[r];
        wxa[g] = p.wih0d[r]; wxb[g] = 0.f;
      }
    }
    const float oW = p.outW[j], ob = p.outb[0];
    const int T = ph ? 180 : 512;
    __syncthreads();

    for (int t = 0; t < T; ++t) {
      // ---- pin weight fragments in AGPRs (opaque redef: no remat/spill;
      //      MFMA reads B-operands from AGPR directly -> zero copies) ----
#pragma unroll
      for (int m = 0; m < 3; ++m)
#pragma unroll
        for (int g = 0; g < 3; ++g)
#pragma unroll
          for (int kf = 0; kf < 2; ++kf)
#pragma unroll
            for (int sp = 0; sp < 2; ++sp)
              asm volatile("" : "+a"(wB[m][g][kf][sp]));

      const int cur = t & 1;
      const unsigned short* h0o = aH0 + (cur ^ 1) * 4096;
      const unsigned short* h1o = aH1 + (cur ^ 1) * 4096;
      unsigned short* h0n = aH0 + cur * 4096;
      unsigned short* h1n = aH1 + cur * 4096;

      // ---- inputs: x (enc) / prev from pw partials (dec) ----
      float2 xx[2][4]; float prevv[2][4];
      if (ph == 0) {
#pragma unroll
        for (int rb = 0; rb < 2; ++rb)
#pragma unroll
          for (int i = 0; i < 4; ++i)
            xx[rb][i] = *(const float2*)(p.x +
                ((size_t)(b0 + rb * 16 + rg * 4 + i) * 512 + t) * 2);
      } else {
        if (t > 0) {
#pragma unroll
          for (int rb = 0; rb < 2; ++rb)
#pragma unroll
            for (int i = 0; i < 4; ++i) {
              int b = rb * 16 + rg * 4 + i;
              prevv[rb][i] = ob + pw[0][b] + pw[1][b] + pw[2][b] + pw[3][b];
            }
          if (w == 0 && jc == 0) {
#pragma unroll
            for (int rb = 0; rb < 2; ++rb)
#pragma unroll
              for (int i = 0; i < 4; ++i)
                p.out[(size_t)(b0 + rb * 16 + rg * 4 + i) * 180 + (t - 1)] =
                    prevv[rb][i];
          }
        } else {
#pragma unroll
          for (int rb = 0; rb < 2; ++rb)
#pragma unroll
            for (int i = 0; i < 4; ++i) prevv[rb][i] = 0.f;
        }
      }

      // ---- A-frag loads: h0(old) + h1(old) prefetch (h1o stable all step) ----
      bf16x8 ah[2][2], al[2][2], qh[2][2], ql[2][2];   // [kf][rb]
#pragma unroll
      for (int kf = 0; kf < 2; ++kf)
#pragma unroll
        for (int rb = 0; rb < 2; ++rb) {
          ah[kf][rb] = *(const bf16x8*)&h0o[rb * 2048 + kf * 1024 + rdb];
          al[kf][rb] = *(const bf16x8*)&h0o[rb * 2048 + kf * 1024 + 512 + rdb];
          qh[kf][rb] = *(const bf16x8*)&h1o[rb * 2048 + kf * 1024 + rdb];
          ql[kf][rb] = *(const bf16x8*)&h1o[rb * 2048 + kf * 1024 + 512 + rdb];
        }

      // ---- cell0 GEMM: Whh0 . h0(old); 6 independent chains ----
      f32x4 aR[2], aZ[2], aN[2];
#pragma unroll
      for (int rb = 0; rb < 2; ++rb) {
        f32x4 zz = {0.f, 0.f, 0.f, 0.f};
        aR[rb] = zz; aZ[rb] = zz; aN[rb] = zz;
      }
#pragma unroll
      for (int kf = 0; kf < 2; ++kf) {
#pragma unroll
        for (int rb = 0; rb < 2; ++rb) {
          aR[rb] = mfma16(ah[kf][rb], wB[0][0][kf][0], aR[rb]);
          aZ[rb] = mfma16(ah[kf][rb], wB[0][1][kf][0], aZ[rb]);
          aN[rb] = mfma16(ah[kf][rb], wB[0][2][kf][0], aN[rb]);
        }
#pragma unroll
        for (int rb = 0; rb < 2; ++rb) {
          aR[rb] = mfma16(al[kf][rb], wB[0][0][kf][0], aR[rb]);
          aZ[rb] = mfma16(al[kf][rb], wB[0][1][kf][0], aZ[rb]);
          aN[rb] = mfma16(al[kf][rb], wB[0][2][kf][0], aN[rb]);
        }
#pragma unroll
        for (int rb = 0; rb < 2; ++rb) {
          aR[rb] = mfma16(ah[kf][rb], wB[0][0][kf][1], aR[rb]);
          aZ[rb] = mfma16(ah[kf][rb], wB[0][1][kf][1], aZ[rb]);
          aN[rb] = mfma16(ah[kf][rb], wB[0][2][kf][1], aN[rb]);
        }
      }
      // ---- gate0 (lane-local), publish h0(new) frags ----
#pragma unroll
      for (int rb = 0; rb < 2; ++rb)
#pragma unroll
        for (int i = 0; i < 4; ++i) {
          float xr, xz, xn;
          if (ph == 0) {
            xr = bi0[0] + wxa[0] * xx[rb][i].x + wxb[0] * xx[rb][i].y;
            xz = bi0[1] + wxa[1] * xx[rb][i].x + wxb[1] * xx[rb][i].y;
            xn = bi0[2] + wxa[2] * xx[rb][i].x + wxb[2] * xx[rb][i].y;
          } else {
            xr = bi0[0] + wxa[0] * prevv[rb][i];
            xz = bi0[1] + wxa[1] * prevv[rb][i];
            xn = bi0[2] + wxa[2] * prevv[rb][i];
          }
          float r = sgm(xr + bh0[0] + aR[rb][i]);
          float z = sgm(xz + bh0[1] + aZ[rb][i]);
          float n = th(xn + r * (bh0[2] + aN[rb][i]));
          h0own[rb][i] = (1.f - z) * n + z * h0own[rb][i];
          unsigned short hi = rbf(h0own[rb][i]);
          unsigned short lo = rbf(h0own[rb][i] - ubf(hi));
          int idx = rb * 2048 + wbase + (((rg * 4 + i) ^ rgj) << 3);
          h0n[idx] = hi; h0n[idx + 512] = lo;
        }
      __syncthreads();   // mid: h0(new) frags complete
      // ---- cell1 dual GEMM: Wih1 . h0(new) ; Whh1 . h1(old) ----
      bf16x8 gh[2][2], gl[2][2];
#pragma unroll
      for (int kf = 0; kf < 2; ++kf)
#pragma unroll
        for (int rb = 0; rb < 2; ++rb) {
          gh[kf][rb] = *(const bf16x8*)&h0n[rb * 2048 + kf * 1024 + rdb];
          gl[kf][rb] = *(const bf16x8*)&h0n[rb * 2048 + kf * 1024 + 512 + rdb];
        }
      f32x4 cR[2], cZ[2], iN2[2], hN2[2];
#pragma unroll
      for (int rb = 0; rb < 2; ++rb) {
        f32x4 zz = {0.f, 0.f, 0.f, 0.f};
        cR[rb] = zz; cZ[rb] = zz; iN2[rb] = zz; hN2[rb] = zz;
      }
#pragma unroll
      for (int kf = 0; kf < 2; ++kf) {
#pragma unroll
        for (int rb = 0; rb < 2; ++rb) {
          cR[rb]  = mfma16(gh[kf][rb], wB[1][0][kf][0], cR[rb]);
          cZ[rb]  = mfma16(gh[kf][rb], wB[1][1][kf][0], cZ[rb]);
          iN2[rb] = mfma16(gh[kf][rb], wB[1][2][kf][0], iN2[rb]);
        }
#pragma unroll
        for (int rb = 0; rb < 2; ++rb) {
          cR[rb]  = mfma16(qh[kf][rb], wB[2][0][kf][0], cR[rb]);
          cZ[rb]  = mfma16(qh[kf][rb], wB[2][1][kf][0], cZ[rb]);
          hN2[rb] = mfma16(qh[kf][rb], wB[2][2][kf][0], hN2[rb]);
        }
#pragma unroll
        for (int rb = 0; rb < 2; ++rb) {
          cR[rb]  = mfma16(gl[kf][rb], wB[1][0][kf][0], cR[rb]);
          cZ[rb]  = mfma16(gl[kf][rb], wB[1][1][kf][0], cZ[rb]);
          iN2[rb] = mfma16(gl[kf][rb], wB[1][2][kf][0], iN2[rb]);
        }
#pragma unroll
        for (int rb = 0; rb < 2; ++rb) {
          cR[rb]  = mfma16(ql[kf][rb], wB[2][0][kf][0], cR[rb]);
          cZ[rb]  = mfma16(ql[kf][rb], wB[2][1][kf][0], cZ[rb]);
          hN2[rb] = mfma16(ql[kf][rb], wB[2][2][kf][0], hN2[rb]);
        }
#pragma unroll
        for (int rb = 0; rb < 2; ++rb) {
          cR[rb]  = mfma16(gh[kf][rb], wB[1][0][kf][1], cR[rb]);
          cZ[rb]  = mfma16(gh[kf][rb], wB[1][1][kf][1], cZ[rb]);
          iN2[rb] = mfma16(gh[kf][rb], wB[1][2][kf][1], iN2[rb]);
        }
#pragma unroll
        for (int rb = 0; rb < 2; ++rb) {
          cR[rb]  = mfma16(qh[kf][rb], wB[2][0][kf][1], cR[rb]);
          cZ[rb]  = mfma16(qh[kf][rb], wB[2][1][kf][1], cZ[rb]);
          hN2[rb] = mfma16(qh[kf][rb], wB[2][2][kf][1], hN2[rb]);
        }
      }
      // ---- gate1 (lane-local), publish h1(new) frags, decoder partials ----
      float v[2][4];
#pragma unroll
      for (int rb = 0; rb < 2; ++rb)
#pragma unroll
        for (int i = 0; i < 4; ++i) {
          float r = sgm(cR[rb][i] + bi1[0] + bh1[0]);
          float z = sgm(cZ[rb][i] + bi1[1] + bh1[1]);
          float n = th(iN2[rb][i] + bi1[2] + r * (bh1[2] + hN2[rb][i]));
          h1own[rb][i] = (1.f - z) * n + z * h1own[rb][i];
          unsigned short hi = rbf(h1own[rb][i]);
          unsigned short lo = rbf(h1own[rb][i] - ubf(hi));
          int idx = rb * 2048 + wbase + (((rg * 4 + i) ^ rgj) << 3);
          h1n[idx] = hi; h1n[idx + 512] = lo;
          v[rb][i] = oW * h1own[rb][i];
        }
      if (ph == 1) {
        // intra-wave reduce over the 16 jc lanes (j covers 16w..16w+15)
#pragma unroll
        for (int off = 1; off < 16; off <<= 1)
#pragma unroll
          for (int rb = 0; rb < 2; ++rb)
#pragma unroll
            for (int i = 0; i < 4; ++i)
              v[rb][i] += __shfl_xor(v[rb][i], off, 64);
        if (jc == 0) {
#pragma unroll
          for (int rb = 0; rb < 2; ++rb)
#pragma unroll
            for (int i = 0; i < 4; ++i)
              pw[w][rb * 16 + rg * 4 + i] = v[rb][i];
        }
      }
      __syncthreads();   // end: h1(new) frags + pw complete
    }
    // ---- decoder tail: emit out[179] from last partials ----
    if (ph == 1) {
      if (w == 0 && jc == 0) {
#pragma unroll
        for (int rb = 0; rb < 2; ++rb)
#pragma unroll
          for (int i = 0; i < 4; ++i) {
            int b = rb * 16 + rg * 4 + i;
            float fv = ob + pw[0][b] + pw[1][b] + pw[2][b] + pw[3][b];
            p.out[(size_t)(b0 + b) * 180 + 179] = fv;
          }
      }
    }
  }
}

extern "C" void kernel_launch(void* const* d_in, const int* in_sizes, int n_in,
                              void* d_out, int out_size, void* d_ws, size_t ws_size,
                              hipStream_t stream) {
  // input order: 0 x, 1 enc_Wih0, 2 enc_Whh0, 3 enc_bih0, 4 enc_bhh0,
  // 5 enc_Wih1, 6 enc_Whh1, 7 enc_bih1, 8 enc_bhh1, 9 dec_Wih0, 10 dec_Whh0,
  // 11 dec_bih0, 12 dec_bhh0, 13 dec_Wih1, 14 dec_Whh1, 15 dec_bih1,
  // 16 dec_bhh1, 17 out_W, 18 out_b
  unsigned short* wt = (unsigned short*)d_ws;  // 6*24576*2 = 294912 B

  prep_w<<<dim3(6), dim3(256), 0, stream>>>(
      (const float*)d_in[2], (const float*)d_in[5], (const float*)d_in[6],
      (const float*)d_in[10], (const float*)d_in[13], (const float*)d_in[14], wt);

  Params p;
  p.x = (const float*)d_in[0];
  p.wih0e = (const float*)d_in[1];
  p.bih0e = (const float*)d_in[3];
  p.bhh0e = (const float*)d_in[4];
  p.bih1e = (const float*)d_in[7];
  p.bhh1e = (const float*)d_in[8];
  p.wih0d = (const float*)d_in[9];
  p.bih0d = (const float*)d_in[11];
  p.bhh0d = (const float*)d_in[12];
  p.bih1d = (const float*)d_in[15];
  p.bhh1d = (const float*)d_in[16];
  p.outW = (const float*)d_in[17];
  p.outb = (const float*)d_in[18];
  p.wt = wt;
  p.out = (float*)d_out;

  gru_main<<<dim3(256), dim3(256), 0, stream>>>(p);
}

// Round 10
// 2467.466 us; speedup vs baseline: 1.0268x; 1.0268x over previous
//
#include <hip/hip_runtime.h>

// GRU encoder-decoder, MFMA split-precision, partial-AGPR weights (r10 =
// r9 + one-line fix: decoder cell0 weight base was p.wt + ph*18432, must be
// p.wt + ph*3*24576 (each matrix = 48*512 ushorts). Encoder was correct,
// decoder cell0 read mid-plane of enc_Whh0 -> absmax 6e-3. Verified index
// algebra: full offset = (mtx*48 + nt*4 + kf*2 + sp)*512, mtx = ph*3+m.)
// B=8192, H=64, 512 enc + 180 dec steps. 512 blocks x 256 threads (4 waves),
// 16 batches/block, 2 blocks/CU -> 2 waves/SIMD.
// Design: cell1's 24 weight frags pinned in AGPRs ("+a", 96 AGPR; MFMA reads
// B from AGPR directly - verified r6); cell0's 12 frags are plain in-loop
// loads from L2-resident wt (loop-invariant addresses). Worst-case unified
// regs ~226 <= 256 (launch_bounds(256,2)). 2 barriers/step.
// Ownership as r4-r6: wave w owns N-tiles {w,4+w,8+w}; lane (rg,jc) gates
// (batch 4rg+i, j=16w+jc) lane-locally; bf16 hi/lo A-frags in LDS,
// XOR-swizzle b^rg (0 bank conflicts, verified r4-r6).

typedef __attribute__((ext_vector_type(8))) short bf16x8;
typedef __attribute__((ext_vector_type(4))) float f32x4;

struct Params {
  const float *x;
  const float *wih0e, *bih0e, *bhh0e, *bih1e, *bhh1e;
  const float *wih0d, *bih0d, *bhh0d, *bih1d, *bhh1d;
  const float *outW, *outb;
  const unsigned short *wt;   // [6][12 nt][2 kf][2 sp][64 lane][8 e] bf16 frags
  float *out;
};

__device__ __forceinline__ float sgm(float v) { return 1.f / (1.f + __expf(-v)); }
__device__ __forceinline__ float th(float v)  { float e = __expf(2.f * v); return 1.f - 2.f / (e + 1.f); }

// fp32 -> bf16 round-to-nearest-even (bit trick)
__device__ __forceinline__ unsigned short rbf(float v) {
  unsigned int u = __float_as_uint(v);
  return (unsigned short)((u + 0x7fffu + ((u >> 16) & 1u)) >> 16);
}
__device__ __forceinline__ float ubf(unsigned short h) {
  return __uint_as_float((unsigned int)h << 16);
}

__device__ __forceinline__ f32x4 mfma16(bf16x8 a, bf16x8 b, f32x4 c) {
  return __builtin_amdgcn_mfma_f32_16x16x32_bf16(a, b, c, 0, 0, 0);
}

// Preprocess the six 192x64 fp32 matrices into B-fragment bf16 hi/lo planes.
// B[k][n] = W[n][k]; frag (nt,kf,sp): lane l elem e holds
// B[k = kf*32 + (l>>4)*8 + e][n = nt*16 + (l&15)].
// Flat: dst[m][ ((nt*2+kf)*2+sp)*512 + l*8 + e ]   (validated r3-r6)
__global__ void prep_w(const float* s0, const float* s1, const float* s2,
                       const float* s3, const float* s4, const float* s5,
                       unsigned short* dst) {
  const float* srcs[6] = {s0, s1, s2, s3, s4, s5};
  const float* s = srcs[blockIdx.x];
  unsigned short* o = dst + blockIdx.x * 24576;
  for (int i = threadIdx.x; i < 24576; i += blockDim.x) {
    int e  = i & 7;
    int l  = (i >> 3) & 63;
    int sp = (i >> 9) & 1;
    int kf = (i >> 10) & 1;
    int nt = i >> 11;
    int n = nt * 16 + (l & 15);
    int k = kf * 32 + (l >> 4) * 8 + e;
    float v = s[n * 64 + k];
    unsigned short hi = rbf(v);
    unsigned short val = hi;
    if (sp) val = rbf(v - ubf(hi));
    o[i] = val;
  }
}

// A-frag LDS layout (per h matrix, per parity buffer), 2048 ushorts = 4KB:
//   idx(kf,sp,rg,bslot,e) = (kf*2+sp)*512 + rg*128 + bslot*8 + e
//   value = h_split[sp][b = bslot ^ rg][k = kf*32 + rg*8 + e]
// Read (lane l): rg=l>>4, bslot=(l&15)^rg -> b128, quarter-wave linear.
// Write (j-owner): kf=j>>5, rg=(j>>3)&3, e=j&7, bslot=b^rg -> <=2-way.

__global__ __launch_bounds__(256, 2) void gru_main(Params p) {
  __shared__ unsigned short aH0[2][2048];
  __shared__ unsigned short aH1[2][2048];
  __shared__ float pw[4][16];

  const int tid = threadIdx.x;
  const int l   = tid & 63;
  const int w   = tid >> 6;        // wave 0..3
  const int jc  = l & 15;
  const int rg  = l >> 4;
  const int j   = w * 16 + jc;     // this lane's hidden/gate index
  const int b0  = blockIdx.x * 16;

  const int kfj = j >> 5, rgj = (j >> 3) & 3, ej = j & 7;
  const int wbase = kfj * 1024 + rgj * 128 + ej;   // +bslot*8; +512 for lo
  const int rdb = rg * 128 + ((jc ^ rg) << 3);

  for (int i = tid; i < 2048; i += 256) {
    aH0[0][i] = 0; aH0[1][i] = 0; aH1[0][i] = 0; aH1[1][i] = 0;
  }
  float h0own[4] = {0.f, 0.f, 0.f, 0.f}, h1own[4] = {0.f, 0.f, 0.f, 0.f};

  bf16x8 wB1[2][3][2][2];  // cell1 matrices {Wih1,Whh1}[gate][kf][sp] - AGPR

  for (int ph = 0; ph < 2; ++ph) {
    // ---- cell0 weight frag base: matrix mtx = ph*3, stride 24576 ushorts ----
    const unsigned short* wt0 = p.wt + (ph * 3) * 24576;
    // ---- load cell1's weight fragments into the pinned AGPR set ----
#pragma unroll
    for (int m = 0; m < 2; ++m)
#pragma unroll
      for (int g = 0; g < 3; ++g)
#pragma unroll
        for (int kf = 0; kf < 2; ++kf)
#pragma unroll
          for (int sp = 0; sp < 2; ++sp) {
            int nt = g * 4 + w;
            wB1[m][g][kf][sp] = *(const bf16x8*)(p.wt +
                (((((ph * 3 + 1 + m) * 12 + nt) * 2 + kf) * 2 + sp) << 9) + l * 8);
          }
    // ---- per-lane constants for row j ----
    float bi0[3], bh0[3], bi1[3], bh1[3], wxa[3], wxb[3];
#pragma unroll
    for (int g = 0; g < 3; ++g) {
      int r = g * 64 + j;
      if (ph == 0) {
        bi0[g] = p.bih0e[r]; bh0[g] = p.bhh0e[r];
        bi1[g] = p.bih1e[r]; bh1[g] = p.bhh1e[r];
        wxa[g] = p.wih0e[2 * r]; wxb[g] = p.wih0e[2 * r + 1];
      } else {
        bi0[g] = p.bih0d[r]; bh0[g] = p.bhh0d[r];
        bi1[g] = p.bih1d[r]; bh1[g] = p.bhh1d[r];
        wxa[g] = p.wih0d[r]; wxb[g] = 0.f;
      }
    }
    const float oW = p.outW[j], ob = p.outb[0];
    const int T = ph ? 180 : 512;
    __syncthreads();

    for (int t = 0; t < T; ++t) {
      // ---- pin cell1 weight fragments in AGPRs (96 AGPR; opaque redef
      //      forbids remat/spill; MFMA reads B from AGPR - verified r6) ----
#pragma unroll
      for (int m = 0; m < 2; ++m)
#pragma unroll
        for (int g = 0; g < 3; ++g)
#pragma unroll
          for (int kf = 0; kf < 2; ++kf)
#pragma unroll
            for (int sp = 0; sp < 2; ++sp)
              asm volatile("" : "+a"(wB1[m][g][kf][sp]));

      const int cur = t & 1;
      const unsigned short* h0o = aH0[cur ^ 1];
      const unsigned short* h1o = aH1[cur ^ 1];
      unsigned short* h0n = aH0[cur];
      unsigned short* h1n = aH1[cur];

      // ---- inputs: x (enc) / prev from pw partials (dec) ----
      float2 xx[4]; float prevv[4];
      if (ph == 0) {
#pragma unroll
        for (int i = 0; i < 4; ++i)
          xx[i] = *(const float2*)(p.x + ((size_t)(b0 + rg * 4 + i) * 512 + t) * 2);
      } else {
        if (t > 0) {
#pragma unroll
          for (int i = 0; i < 4; ++i)
            prevv[i] = ob + pw[0][rg * 4 + i] + pw[1][rg * 4 + i]
                          + pw[2][rg * 4 + i] + pw[3][rg * 4 + i];
          if (w == 0 && jc == 0) {
#pragma unroll
            for (int i = 0; i < 4; ++i)
              p.out[(size_t)(b0 + rg * 4 + i) * 180 + (t - 1)] = prevv[i];
          }
        } else {
#pragma unroll
          for (int i = 0; i < 4; ++i) prevv[i] = 0.f;
        }
      }

      // ---- cell0 weight frags (L2-resident, loop-invariant addresses) ----
      bf16x8 w0[3][2][2];
#pragma unroll
      for (int g = 0; g < 3; ++g)
#pragma unroll
        for (int kf = 0; kf < 2; ++kf)
#pragma unroll
          for (int sp = 0; sp < 2; ++sp)
            w0[g][kf][sp] = *(const bf16x8*)(wt0 +
                ((((g * 4 + w) * 2 + kf) * 2 + sp) << 9) + l * 8);

      // ---- A-frag loads: h0(old) + h1(old) prefetch ----
      bf16x8 ah[2], al[2], qh[2], ql[2];
#pragma unroll
      for (int kf = 0; kf < 2; ++kf) {
        ah[kf] = *(const bf16x8*)&h0o[kf * 1024 + rdb];
        al[kf] = *(const bf16x8*)&h0o[kf * 1024 + 512 + rdb];
        qh[kf] = *(const bf16x8*)&h1o[kf * 1024 + rdb];
        ql[kf] = *(const bf16x8*)&h1o[kf * 1024 + 512 + rdb];
      }
      // ---- cell0 GEMM: Whh0 . h0(old) ----
      f32x4 aR = {0,0,0,0}, aZ = {0,0,0,0}, aN = {0,0,0,0};
#pragma unroll
      for (int kf = 0; kf < 2; ++kf) {
        aR = mfma16(ah[kf], w0[0][kf][0], aR);
        aZ = mfma16(ah[kf], w0[1][kf][0], aZ);
        aN = mfma16(ah[kf], w0[2][kf][0], aN);
        aR = mfma16(al[kf], w0[0][kf][0], aR);
        aZ = mfma16(al[kf], w0[1][kf][0], aZ);
        aN = mfma16(al[kf], w0[2][kf][0], aN);
        aR = mfma16(ah[kf], w0[0][kf][1], aR);
        aZ = mfma16(ah[kf], w0[1][kf][1], aZ);
        aN = mfma16(ah[kf], w0[2][kf][1], aN);
      }
      // ---- gate0 (lane-local), publish h0(new) frags ----
#pragma unroll
      for (int i = 0; i < 4; ++i) {
        float xr, xz, xn;
        if (ph == 0) {
          xr = bi0[0] + wxa[0] * xx[i].x + wxb[0] * xx[i].y;
          xz = bi0[1] + wxa[1] * xx[i].x + wxb[1] * xx[i].y;
          xn = bi0[2] + wxa[2] * xx[i].x + wxb[2] * xx[i].y;
        } else {
          xr = bi0[0] + wxa[0] * prevv[i];
          xz = bi0[1] + wxa[1] * prevv[i];
          xn = bi0[2] + wxa[2] * prevv[i];
        }
        float r = sgm(xr + bh0[0] + aR[i]);
        float z = sgm(xz + bh0[1] + aZ[i]);
        float n = th(xn + r * (bh0[2] + aN[i]));
        h0own[i] = (1.f - z) * n + z * h0own[i];
        unsigned short hi = rbf(h0own[i]);
        unsigned short lo = rbf(h0own[i] - ubf(hi));
        int idx = wbase + (((rg * 4 + i) ^ rgj) << 3);
        h0n[idx] = hi; h0n[idx + 512] = lo;
      }
      __syncthreads();   // MID: h0(new) frags complete
      // ---- cell1 dual GEMM: Wih1 . h0(new) ; Whh1 . h1(old) ----
      bf16x8 gh[2], gl[2];
#pragma unroll
      for (int kf = 0; kf < 2; ++kf) {
        gh[kf] = *(const bf16x8*)&h0n[kf * 1024 + rdb];
        gl[kf] = *(const bf16x8*)&h0n[kf * 1024 + 512 + rdb];
      }
      f32x4 cR = {0,0,0,0}, cZ = {0,0,0,0}, iN = {0,0,0,0}, hN = {0,0,0,0};
#pragma unroll
      for (int kf = 0; kf < 2; ++kf) {
        cR = mfma16(gh[kf], wB1[0][0][kf][0], cR);
        cZ = mfma16(gh[kf], wB1[0][1][kf][0], cZ);
        iN = mfma16(gh[kf], wB1[0][2][kf][0], iN);
        cR = mfma16(qh[kf], wB1[1][0][kf][0], cR);
        cZ = mfma16(qh[kf], wB1[1][1][kf][0], cZ);
        hN = mfma16(qh[kf], wB1[1][2][kf][0], hN);
        cR = mfma16(gl[kf], wB1[0][0][kf][0], cR);
        cZ = mfma16(gl[kf], wB1[0][1][kf][0], cZ);
        iN = mfma16(gl[kf], wB1[0][2][kf][0], iN);
        cR = mfma16(ql[kf], wB1[1][0][kf][0], cR);
        cZ = mfma16(ql[kf], wB1[1][1][kf][0], cZ);
        hN = mfma16(ql[kf], wB1[1][2][kf][0], hN);
        cR = mfma16(gh[kf], wB1[0][0][kf][1], cR);
        cZ = mfma16(gh[kf], wB1[0][1][kf][1], cZ);
        iN = mfma16(gh[kf], wB1[0][2][kf][1], iN);
        cR = mfma16(qh[kf], wB1[1][0][kf][1], cR);
        cZ = mfma16(qh[kf], wB1[1][1][kf][1], cZ);
        hN = mfma16(qh[kf], wB1[1][2][kf][1], hN);
      }
      // ---- gate1 (lane-local), publish h1(new) frags, decoder partials ----
      float v[4];
#pragma unroll
      for (int i = 0; i < 4; ++i) {
        float r = sgm(cR[i] + bi1[0] + bh1[0]);
        float z = sgm(cZ[i] + bi1[1] + bh1[1]);
        float n = th(iN[i] + bi1[2] + r * (bh1[2] + hN[i]));
        h1own[i] = (1.f - z) * n + z * h1own[i];
        unsigned short hi = rbf(h1own[i]);
        unsigned short lo = rbf(h1own[i] - ubf(hi));
        int idx = wbase + (((rg * 4 + i) ^ rgj) << 3);
        h1n[idx] = hi; h1n[idx + 512] = lo;
        v[i] = oW * h1own[i];
      }
      if (ph == 1) {
        // intra-wave reduce over the 16 jc lanes (j covers 16w..16w+15)
#pragma unroll
        for (int off = 1; off < 16; off <<= 1)
#pragma unroll
          for (int i = 0; i < 4; ++i) v[i] += __shfl_xor(v[i], off, 64);
        if (jc == 0) {
#pragma unroll
          for (int i = 0; i < 4; ++i) pw[w][rg * 4 + i] = v[i];
        }
      }
      __syncthreads();   // END: h1(new) + pw stable for next step
    }
    // ---- decoder tail: emit out[179] from last partials ----
    if (ph == 1) {
      if (w == 0 && jc == 0) {
#pragma unroll
        for (int i = 0; i < 4; ++i) {
          float fv = ob + pw[0][rg * 4 + i] + pw[1][rg * 4 + i]
                        + pw[2][rg * 4 + i] + pw[3][rg * 4 + i];
          p.out[(size_t)(b0 + rg * 4 + i) * 180 + 179] = fv;
        }
      }
    }
  }
}

extern "C" void kernel_launch(void* const* d_in, const int* in_sizes, int n_in,
                              void* d_out, int out_size, void* d_ws, size_t ws_size,
                              hipStream_t stream) {
  // input order: 0 x, 1 enc_Wih0, 2 enc_Whh0, 3 enc_bih0, 4 enc_bhh0,
  // 5 enc_Wih1, 6 enc_Whh1, 7 enc_bih1, 8 enc_bhh1, 9 dec_Wih0, 10 dec_Whh0,
  // 11 dec_bih0, 12 dec_bhh0, 13 dec_Wih1, 14 dec_Whh1, 15 dec_bih1,
  // 16 dec_bhh1, 17 out_W, 18 out_b
  unsigned short* wt = (unsigned short*)d_ws;  // 6*24576*2 = 294912 B

  prep_w<<<dim3(6), dim3(256), 0, stream>>>(
      (const float*)d_in[2], (const float*)d_in[5], (const float*)d_in[6],
      (const float*)d_in[10], (const float*)d_in[13], (const float*)d_in[14], wt);

  Params p;
  p.x = (const float*)d_in[0];
  p.wih0e = (const float*)d_in[1];
  p.bih0e = (const float*)d_in[3];
  p.bhh0e = (const float*)d_in[4];
  p.bih1e = (const float*)d_in[7];
  p.bhh1e = (const float*)d_in[8];
  p.wih0d = (const float*)d_in[9];
  p.bih0d = (const float*)d_in[11];
  p.bhh0d = (const float*)d_in[12];
  p.bih1d = (const float*)d_in[15];
  p.bhh1d = (const float*)d_in[16];
  p.outW = (const float*)d_in[17];
  p.outb = (const float*)d_in[18];
  p.wt = wt;
  p.out = (float*)d_out;

  gru_main<<<dim3(512), dim3(256), 0, stream>>>(p);
}